// Round 1
// baseline (187.542 us; speedup 1.0000x reference)
//
#include <hip/hip_runtime.h>
#include <hip/hip_bf16.h>

#define NNODES 50000
#define KNBR   17
#define DF     128
#define NEDGE  (NNODES*KNBR)
#define BN_EPS 1e-5f
#define SLOPE  0.01f

// ---- workspace layout (in floats) ----
#define NBLK_BN 256
#define OFF_PART 0                          // 256 blocks * 256 floats
#define OFF_SS   (NBLK_BN*256)              // 65536 : scale[128], shift[128]
#define OFF_HT   (OFF_SS + 256)             // 65792 : Ht [N][128]
#define OFF_OUT  (OFF_HT + NNODES*DF)       // Outl [N][128]
#define OFF_SC   (OFF_OUT + NNODES*DF)      // scores [NEDGE]

// ---------------- K1: BatchNorm stats (partial sums, no atomics) -------------
__global__ __launch_bounds__(256) void bn_stats(const float* __restrict__ H,
                                                float* __restrict__ part) {
    const int tid = threadIdx.x;
    const int cg = tid & 31;   // float4 column group (4 cols)
    const int rg = tid >> 5;   // 0..7 row group
    const float4* H4 = (const float4*)H;
    float4 s = {0,0,0,0}, q = {0,0,0,0};
    for (int r = blockIdx.x*8 + rg; r < NNODES; r += gridDim.x*8) {
        float4 v = H4[r*32 + cg];
        s.x += v.x; s.y += v.y; s.z += v.z; s.w += v.w;
        q.x = fmaf(v.x, v.x, q.x); q.y = fmaf(v.y, v.y, q.y);
        q.z = fmaf(v.z, v.z, q.z); q.w = fmaf(v.w, v.w, q.w);
    }
    __shared__ float red[8][32][8];
    red[rg][cg][0] = s.x; red[rg][cg][1] = s.y; red[rg][cg][2] = s.z; red[rg][cg][3] = s.w;
    red[rg][cg][4] = q.x; red[rg][cg][5] = q.y; red[rg][cg][6] = q.z; red[rg][cg][7] = q.w;
    __syncthreads();
    // 256 outputs per block: [cg2][slot]; slot<4 = sum of col 4*cg2+slot, slot>=4 sumsq
    float v = 0.f;
    const int cg2 = tid >> 3, slot = tid & 7;
    #pragma unroll
    for (int g = 0; g < 8; ++g) v += red[g][cg2][slot];
    part[blockIdx.x*256 + tid] = v;
}

// ---------------- K2: finalize -> scale/shift --------------------------------
__global__ __launch_bounds__(256) void bn_finalize(const float* __restrict__ part,
                                                   const float* __restrict__ gamma,
                                                   const float* __restrict__ beta,
                                                   float* __restrict__ ss) {
    __shared__ float tot[256];
    const int t = threadIdx.x;
    float v = 0.f;
    for (int b = 0; b < NBLK_BN; ++b) v += part[b*256 + t];
    tot[t] = v;
    __syncthreads();
    if (t < 128) {
        const int cg = t >> 2, sl = t & 3;
        const float sum = tot[cg*8 + sl];
        const float sq  = tot[cg*8 + 4 + sl];
        const float mean = sum * (1.0f/NNODES);
        const float var  = sq * (1.0f/NNODES) - mean*mean;
        const float sc = rsqrtf(var + BN_EPS) * gamma[t];
        ss[t]       = sc;
        ss[128 + t] = beta[t] - mean*sc;
    }
}

// ---------------- K3: fused dual GEMM: Ht = Hn@Wt+bt ; Outl = Hn@Wo+bo -------
// block 256 thr; tile 64 rows x 256 cols; thread tile 8x8; K slabs of 32.
__global__ __launch_bounds__(256) void dual_gemm(const float* __restrict__ H,
                                                 const float* __restrict__ ss,
                                                 const float* __restrict__ Wt,
                                                 const float* __restrict__ bt,
                                                 const float* __restrict__ Wo,
                                                 const float* __restrict__ bo,
                                                 float* __restrict__ Ht,
                                                 float* __restrict__ Outl) {
    __shared__ float a_lds[32][68];    // [k][row], padded
    __shared__ float b_lds[32][260];   // [k][col 0..255], padded
    const int tid  = threadIdx.x;
    const int tcol = tid & 31;         // cols [8*tcol, 8*tcol+8)
    const int trow = tid >> 5;         // rows [8*trow, 8*trow+8)
    const int row0 = blockIdx.x * 64;
    const float4* ss4 = (const float4*)ss;
    float acc[8][8] = {};

    for (int kc = 0; kc < 128; kc += 32) {
        __syncthreads();
        // B slab: 32 k x 256 cols (Wt | Wo)
        #pragma unroll
        for (int it = 0; it < 4; ++it) {
            const int q = tid + it*256;           // 0..1023
            const int k = q >> 5, c4 = q & 31;
            const float4 wt = ((const float4*)Wt)[(kc + k)*32 + c4];
            const float4 wo = ((const float4*)Wo)[(kc + k)*32 + c4];
            *(float4*)&b_lds[k][4*c4]        = wt;
            *(float4*)&b_lds[k][128 + 4*c4]  = wo;
        }
        // A slab: 64 rows x 32 k of Hn (BN applied on the fly), stored [k][row]
        #pragma unroll
        for (int it = 0; it < 2; ++it) {
            const int q = tid + it*256;           // 0..511
            const int r = q >> 3, k4 = q & 7;
            const int row = row0 + r;
            float4 v = {0,0,0,0};
            if (row < NNODES) v = ((const float4*)H)[row*32 + (kc>>2) + k4];
            const float4 sc = ss4[(kc>>2) + k4];
            const float4 sh = ss4[32 + (kc>>2) + k4];
            a_lds[4*k4+0][r] = fmaf(v.x, sc.x, sh.x);
            a_lds[4*k4+1][r] = fmaf(v.y, sc.y, sh.y);
            a_lds[4*k4+2][r] = fmaf(v.z, sc.z, sh.z);
            a_lds[4*k4+3][r] = fmaf(v.w, sc.w, sh.w);
        }
        __syncthreads();
        #pragma unroll 2
        for (int k = 0; k < 32; ++k) {
            const float4 a0 = *(const float4*)&a_lds[k][8*trow];
            const float4 a1 = *(const float4*)&a_lds[k][8*trow + 4];
            const float4 b0 = *(const float4*)&b_lds[k][8*tcol];
            const float4 b1 = *(const float4*)&b_lds[k][8*tcol + 4];
            const float a[8] = {a0.x,a0.y,a0.z,a0.w,a1.x,a1.y,a1.z,a1.w};
            const float b[8] = {b0.x,b0.y,b0.z,b0.w,b1.x,b1.y,b1.z,b1.w};
            #pragma unroll
            for (int ri = 0; ri < 8; ++ri)
                #pragma unroll
                for (int ci = 0; ci < 8; ++ci)
                    acc[ri][ci] = fmaf(a[ri], b[ci], acc[ri][ci]);
        }
    }
    // epilogue: +bias, store to Ht (cols<128) or Outl
    float* dst; const float* bias; int cbase;
    if (tcol < 16) { dst = Ht;   bias = bt; cbase = 8*tcol; }
    else           { dst = Outl; bias = bo; cbase = 8*tcol - 128; }
    const float4 bi0 = ((const float4*)bias)[cbase >> 2];
    const float4 bi1 = ((const float4*)bias)[(cbase >> 2) + 1];
    #pragma unroll
    for (int ri = 0; ri < 8; ++ri) {
        const int row = row0 + 8*trow + ri;
        if (row < NNODES) {
            float4 o0 = {acc[ri][0]+bi0.x, acc[ri][1]+bi0.y, acc[ri][2]+bi0.z, acc[ri][3]+bi0.w};
            float4 o1 = {acc[ri][4]+bi1.x, acc[ri][5]+bi1.y, acc[ri][6]+bi1.z, acc[ri][7]+bi1.w};
            *(float4*)&dst[(size_t)row*128 + cbase]     = o0;
            *(float4*)&dst[(size_t)row*128 + cbase + 4] = o1;
        }
    }
}

// ---------------- K4: per-edge attention scores ------------------------------
// 4 lanes per edge; lane covers interleaved float4s so each group load is 64B contiguous.
__global__ __launch_bounds__(256) void edge_scores(const float* __restrict__ Ht,
                                                   const int* __restrict__ col,
                                                   float* __restrict__ scores) {
    const int tid  = threadIdx.x;
    const int lane = tid & 63;
    const int waveG = (blockIdx.x*256 + tid) >> 6;
    const int g = lane >> 2, s = lane & 3;
    const int e = waveG*16 + g;
    if (e >= NEDGE) return;                 // uniform within each 4-lane group
    const int i = e / KNBR;
    const int j = col[e];
    const float4* Hi = (const float4*)(Ht + (size_t)i*DF);
    const float4* Hj = (const float4*)(Ht + (size_t)j*DF);
    float4 acc = {0,0,0,0};
    #pragma unroll
    for (int kk = 0; kk < 8; ++kk) {
        const int idx = kk*4 + s;           // group covers 64B contiguous per kk
        const float4 a = Hi[idx];
        const float4 b = Hj[idx];
        acc.x = fmaf(a.x, b.x, acc.x); acc.y = fmaf(a.y, b.y, acc.y);
        acc.z = fmaf(a.z, b.z, acc.z); acc.w = fmaf(a.w, b.w, acc.w);
    }
    float h = (acc.x + acc.y) + (acc.z + acc.w);
    h += __shfl_xor(h, 1);
    h += __shfl_xor(h, 2);
    if (s == 0) scores[e] = 1.0f / (1.0f + __expf(-h));
}

// ---------------- K5: softmax over K=17 + weighted agg + LeakyReLU -----------
__global__ __launch_bounds__(128) void softmax_agg(const float* __restrict__ scores,
                                                   const int* __restrict__ col,
                                                   const float* __restrict__ Outl,
                                                   float* __restrict__ outF,
                                                   float* __restrict__ Aout) {
    const int i = blockIdx.x;
    const int t = threadIdx.x;
    __shared__ int   jj[KNBR];
    __shared__ float sc_s[KNBR];
    __shared__ float ex[KNBR];
    if (t < KNBR) {
        const int e = i*KNBR + t;
        jj[t]   = col[e];
        sc_s[t] = scores[e];
    }
    __syncthreads();
    float m = -1e30f;
    #pragma unroll
    for (int k = 0; k < KNBR; ++k) m = fmaxf(m, sc_s[k]);
    if (t < KNBR) ex[t] = __expf(sc_s[t] - m);
    __syncthreads();
    float sum = 0.f;
    #pragma unroll
    for (int k = 0; k < KNBR; ++k) sum += ex[k];
    const float rs = 1.0f / sum;
    if (t < KNBR) Aout[(size_t)i*KNBR + t] = ex[t] * rs;
    float acc = 0.f;
    #pragma unroll
    for (int k = 0; k < KNBR; ++k)
        acc = fmaf(ex[k]*rs, Outl[(size_t)jj[k]*DF + t], acc);
    outF[(size_t)i*DF + t] = (acc >= 0.f) ? acc : SLOPE*acc;
}

extern "C" void kernel_launch(void* const* d_in, const int* in_sizes, int n_in,
                              void* d_out, int out_size, void* d_ws, size_t ws_size,
                              hipStream_t stream) {
    const float* H     = (const float*)d_in[0];
    const int*   col   = (const int*)  d_in[1];
    // d_in[2] = row (== e/17 analytically, unused)
    const float* gamma = (const float*)d_in[3];
    const float* beta  = (const float*)d_in[4];
    const float* Wt    = (const float*)d_in[5];
    const float* bt    = (const float*)d_in[6];
    const float* Wo    = (const float*)d_in[7];
    const float* bo    = (const float*)d_in[8];

    float* ws   = (float*)d_ws;
    float* part = ws + OFF_PART;
    float* ss   = ws + OFF_SS;
    float* Ht   = ws + OFF_HT;
    float* Outl = ws + OFF_OUT;
    float* sc   = ws + OFF_SC;

    float* outF = (float*)d_out;
    float* Aout = outF + (size_t)NNODES*DF;

    bn_stats   <<<dim3(NBLK_BN), dim3(256), 0, stream>>>(H, part);
    bn_finalize<<<dim3(1),       dim3(256), 0, stream>>>(part, gamma, beta, ss);
    dual_gemm  <<<dim3((NNODES+63)/64), dim3(256), 0, stream>>>(H, ss, Wt, bt, Wo, bo, Ht, Outl);
    const int waves = (NEDGE + 15)/16;
    edge_scores<<<dim3((waves+3)/4), dim3(256), 0, stream>>>(Ht, col, sc);
    softmax_agg<<<dim3(NNODES), dim3(128), 0, stream>>>(sc, col, Outl, outF, Aout);
}

// Round 2
// 148.620 us; speedup vs baseline: 1.2619x; 1.2619x over previous
//
#include <hip/hip_runtime.h>
#include <hip/hip_bf16.h>

#define NNODES 50000
#define KNBR   17
#define DF     128
#define NEDGE  (NNODES*KNBR)
#define BN_EPS 1e-5f
#define SLOPE  0.01f

// ---- workspace layout (in floats) ----
#define NBLK_BN 256
#define OFF_PART 0                          // 256 blocks * 256 floats
#define OFF_SS   (NBLK_BN*256)              // scale[128], shift[128]
#define OFF_C    (OFF_SS + 256)             // C: N rows x 512B (256 bf16, interleaved h/y pairs)

__device__ __forceinline__ float bfhi(unsigned u) {
    u &= 0xffff0000u; return __builtin_bit_cast(float, u);
}
__device__ __forceinline__ float bflo(unsigned u) {
    u <<= 16; return __builtin_bit_cast(float, u);
}
__device__ __forceinline__ unsigned pack2bf(float x, float y) {
    __hip_bfloat16 a = __float2bfloat16(x), b = __float2bfloat16(y);
    unsigned short ua = __builtin_bit_cast(unsigned short, a);
    unsigned short ub = __builtin_bit_cast(unsigned short, b);
    return (unsigned)ua | ((unsigned)ub << 16);
}

// ---------------- K1: BatchNorm stats (partial sums, no atomics) -------------
__global__ __launch_bounds__(256) void bn_stats(const float* __restrict__ H,
                                                float* __restrict__ part) {
    const int tid = threadIdx.x;
    const int cg = tid & 31;   // float4 column group (4 cols)
    const int rg = tid >> 5;   // 0..7 row group
    const float4* H4 = (const float4*)H;
    float4 s = {0,0,0,0}, q = {0,0,0,0};
    for (int r = blockIdx.x*8 + rg; r < NNODES; r += gridDim.x*8) {
        float4 v = H4[r*32 + cg];
        s.x += v.x; s.y += v.y; s.z += v.z; s.w += v.w;
        q.x = fmaf(v.x, v.x, q.x); q.y = fmaf(v.y, v.y, q.y);
        q.z = fmaf(v.z, v.z, q.z); q.w = fmaf(v.w, v.w, q.w);
    }
    __shared__ float red[8][32][8];
    red[rg][cg][0] = s.x; red[rg][cg][1] = s.y; red[rg][cg][2] = s.z; red[rg][cg][3] = s.w;
    red[rg][cg][4] = q.x; red[rg][cg][5] = q.y; red[rg][cg][6] = q.z; red[rg][cg][7] = q.w;
    __syncthreads();
    float v = 0.f;
    const int cg2 = tid >> 3, slot = tid & 7;
    #pragma unroll
    for (int g = 0; g < 8; ++g) v += red[g][cg2][slot];
    part[blockIdx.x*256 + tid] = v;
}

// ---------------- K2: finalize -> scale/shift --------------------------------
__global__ __launch_bounds__(256) void bn_finalize(const float* __restrict__ part,
                                                   const float* __restrict__ gamma,
                                                   const float* __restrict__ beta,
                                                   float* __restrict__ ss) {
    __shared__ float tot[256];
    const int t = threadIdx.x;
    float v = 0.f;
    for (int b = 0; b < NBLK_BN; ++b) v += part[b*256 + t];
    tot[t] = v;
    __syncthreads();
    if (t < 128) {
        const int cg = t >> 2, sl = t & 3;
        const float sum = tot[cg*8 + sl];
        const float sq  = tot[cg*8 + 4 + sl];
        const float mean = sum * (1.0f/NNODES);
        const float var  = sq * (1.0f/NNODES) - mean*mean;
        const float sc = rsqrtf(var + BN_EPS) * gamma[t];
        ss[t]       = sc;
        ss[128 + t] = beta[t] - mean*sc;
    }
}

// ---------------- K3: fused dual GEMM -> interleaved bf16 rows ---------------
// C row i (512B): for colpair c in [0,64): uint[2c] = bf16x2(Ht[2c],Ht[2c+1]),
//                                          uint[2c+1] = bf16x2(Out[2c],Out[2c+1])
__global__ __launch_bounds__(256) void dual_gemm(const float* __restrict__ H,
                                                 const float* __restrict__ ss,
                                                 const float* __restrict__ Wt,
                                                 const float* __restrict__ bt,
                                                 const float* __restrict__ Wo,
                                                 const float* __restrict__ bo,
                                                 unsigned* __restrict__ C32) {
    __shared__ float a_lds[32][68];    // [k][row], padded
    __shared__ float b_lds[32][260];   // [k][col 0..255], padded
    const int tid  = threadIdx.x;
    const int tcol = tid & 31;         // cols [8*tcol, 8*tcol+8)
    const int trow = tid >> 5;         // rows [8*trow, 8*trow+8)
    const int row0 = blockIdx.x * 64;
    const float4* ss4 = (const float4*)ss;
    float acc[8][8] = {};

    for (int kc = 0; kc < 128; kc += 32) {
        __syncthreads();
        #pragma unroll
        for (int it = 0; it < 4; ++it) {
            const int q = tid + it*256;           // 0..1023
            const int k = q >> 5, c4 = q & 31;
            const float4 wt = ((const float4*)Wt)[(kc + k)*32 + c4];
            const float4 wo = ((const float4*)Wo)[(kc + k)*32 + c4];
            *(float4*)&b_lds[k][4*c4]        = wt;
            *(float4*)&b_lds[k][128 + 4*c4]  = wo;
        }
        #pragma unroll
        for (int it = 0; it < 2; ++it) {
            const int q = tid + it*256;           // 0..511
            const int r = q >> 3, k4 = q & 7;
            const int row = row0 + r;
            float4 v = {0,0,0,0};
            if (row < NNODES) v = ((const float4*)H)[row*32 + (kc>>2) + k4];
            const float4 sc = ss4[(kc>>2) + k4];
            const float4 sh = ss4[32 + (kc>>2) + k4];
            a_lds[4*k4+0][r] = fmaf(v.x, sc.x, sh.x);
            a_lds[4*k4+1][r] = fmaf(v.y, sc.y, sh.y);
            a_lds[4*k4+2][r] = fmaf(v.z, sc.z, sh.z);
            a_lds[4*k4+3][r] = fmaf(v.w, sc.w, sh.w);
        }
        __syncthreads();
        #pragma unroll 2
        for (int k = 0; k < 32; ++k) {
            const float4 a0 = *(const float4*)&a_lds[k][8*trow];
            const float4 a1 = *(const float4*)&a_lds[k][8*trow + 4];
            const float4 b0 = *(const float4*)&b_lds[k][8*tcol];
            const float4 b1 = *(const float4*)&b_lds[k][8*tcol + 4];
            const float a[8] = {a0.x,a0.y,a0.z,a0.w,a1.x,a1.y,a1.z,a1.w};
            const float b[8] = {b0.x,b0.y,b0.z,b0.w,b1.x,b1.y,b1.z,b1.w};
            #pragma unroll
            for (int ri = 0; ri < 8; ++ri)
                #pragma unroll
                for (int ci = 0; ci < 8; ++ci)
                    acc[ri][ci] = fmaf(a[ri], b[ci], acc[ri][ci]);
        }
    }
    // epilogue: +bias -> bf16 pairs into interleaved C row
    const bool isY  = (tcol >= 16);
    const int cbase = isY ? (8*tcol - 128) : (8*tcol);   // column base within 128
    const float* bias = isY ? bo : bt;
    float b8[8];
    #pragma unroll
    for (int ci = 0; ci < 8; ++ci) b8[ci] = bias[cbase + ci];
    #pragma unroll
    for (int ri = 0; ri < 8; ++ri) {
        const int row = row0 + 8*trow + ri;
        if (row < NNODES) {
            unsigned* dst = C32 + (size_t)row*128;
            #pragma unroll
            for (int ci = 0; ci < 4; ++ci) {
                const int cp = (cbase >> 1) + ci;     // colpair index
                dst[2*cp + (isY ? 1 : 0)] =
                    pack2bf(acc[ri][2*ci] + b8[2*ci], acc[ri][2*ci+1] + b8[2*ci+1]);
            }
        }
    }
}

// ---------------- K4: fused scores + softmax + aggregation -------------------
// one 64-lane wave per node; lane l owns colpair l (cols 2l, 2l+1)
__global__ __launch_bounds__(256) void fused_attn(const unsigned* __restrict__ C32,
                                                  const int* __restrict__ col,
                                                  float* __restrict__ outF,
                                                  float* __restrict__ Aout) {
    const int tid  = threadIdx.x;
    const int lane = tid & 63;
    const int i    = (blockIdx.x*256 + tid) >> 6;
    if (i >= NNODES) return;
    const uint2* base = (const uint2*)C32;   // one uint2 per colpair

    // center h
    const uint2 cv = base[(size_t)i*64 + lane];
    const float a0 = bflo(cv.x), a1 = bfhi(cv.x);

    int myj = 0;
    if (lane < KNBR) myj = col[i*KNBR + lane];

    float p[KNBR], y0[KNBR], y1[KNBR];
    #pragma unroll
    for (int k = 0; k < KNBR; ++k) {
        const int j = __shfl(myj, k);
        const uint2 v = base[(size_t)j*64 + lane];
        const float b0 = bflo(v.x), b1 = bfhi(v.x);
        y0[k] = bflo(v.y); y1[k] = bfhi(v.y);
        p[k] = fmaf(a0, b0, a1*b1);
    }
    // butterfly reduce each dot over the 64 lanes
    #pragma unroll
    for (int k = 0; k < KNBR; ++k) {
        float v = p[k];
        v += __shfl_xor(v, 1);  v += __shfl_xor(v, 2);  v += __shfl_xor(v, 4);
        v += __shfl_xor(v, 8);  v += __shfl_xor(v, 16); v += __shfl_xor(v, 32);
        p[k] = v;
    }
    // sigmoid -> softmax (redundant across lanes; all values in registers)
    float m = -1e30f;
    #pragma unroll
    for (int k = 0; k < KNBR; ++k) {
        p[k] = 1.0f / (1.0f + __expf(-p[k]));
        m = fmaxf(m, p[k]);
    }
    float sum = 0.f;
    #pragma unroll
    for (int k = 0; k < KNBR; ++k) { p[k] = __expf(p[k] - m); sum += p[k]; }
    const float rs = 1.0f / sum;

    // write A: lane k writes A_k (static-index select to avoid scratch)
    float myA = 0.f;
    #pragma unroll
    for (int k = 0; k < KNBR; ++k) if (lane == k) myA = p[k]*rs;
    if (lane < KNBR) Aout[(size_t)i*KNBR + lane] = myA;

    // weighted aggregation + LeakyReLU
    float acc0 = 0.f, acc1 = 0.f;
    #pragma unroll
    for (int k = 0; k < KNBR; ++k) {
        const float A = p[k]*rs;
        acc0 = fmaf(A, y0[k], acc0);
        acc1 = fmaf(A, y1[k], acc1);
    }
    acc0 = (acc0 >= 0.f) ? acc0 : SLOPE*acc0;
    acc1 = (acc1 >= 0.f) ? acc1 : SLOPE*acc1;
    float2 o = {acc0, acc1};
    *(float2*)&outF[(size_t)i*DF + 2*lane] = o;
}

extern "C" void kernel_launch(void* const* d_in, const int* in_sizes, int n_in,
                              void* d_out, int out_size, void* d_ws, size_t ws_size,
                              hipStream_t stream) {
    const float* H     = (const float*)d_in[0];
    const int*   col   = (const int*)  d_in[1];
    // d_in[2] = row (== e/17 analytically, unused)
    const float* gamma = (const float*)d_in[3];
    const float* beta  = (const float*)d_in[4];
    const float* Wt    = (const float*)d_in[5];
    const float* bt    = (const float*)d_in[6];
    const float* Wo    = (const float*)d_in[7];
    const float* bo    = (const float*)d_in[8];

    float* ws   = (float*)d_ws;
    float* part = ws + OFF_PART;
    float* ss   = ws + OFF_SS;
    unsigned* C32 = (unsigned*)(ws + OFF_C);

    float* outF = (float*)d_out;
    float* Aout = outF + (size_t)NNODES*DF;

    bn_stats   <<<dim3(NBLK_BN), dim3(256), 0, stream>>>(H, part);
    bn_finalize<<<dim3(1),       dim3(256), 0, stream>>>(part, gamma, beta, ss);
    dual_gemm  <<<dim3((NNODES+63)/64), dim3(256), 0, stream>>>(H, ss, Wt, bt, Wo, bo, C32);
    fused_attn <<<dim3((NNODES+3)/4), dim3(256), 0, stream>>>(C32, col, outF, Aout);
}

// Round 4
// 100.290 us; speedup vs baseline: 1.8700x; 1.4819x over previous
//
#include <hip/hip_runtime.h>
#include <hip/hip_bf16.h>

#define NNODES 50000
#define KNBR   17
#define DF     128
#define NEDGE  (NNODES*KNBR)
#define BN_EPS 1e-5f
#define SLOPE  0.01f

// ---- workspace layout (in floats) ----
#define NBLK_BN 256
#define OFF_PART 0                          // 256 blocks * 256 floats
#define OFF_SS   (NBLK_BN*256)              // scale[128], shift[128]
#define OFF_C    (OFF_SS + 256)             // C: 50048 rows x 512B (uint2/lane: h fp16x2, y fp16x2)

typedef __fp16  h2_t   __attribute__((ext_vector_type(2)));
typedef short   short8 __attribute__((ext_vector_type(8)));
typedef float   f32x4  __attribute__((ext_vector_type(4)));

__device__ __forceinline__ unsigned pack2bf(float x, float y) {
    __hip_bfloat16 a = __float2bfloat16(x), b = __float2bfloat16(y);
    unsigned short ua = __builtin_bit_cast(unsigned short, a);
    unsigned short ub = __builtin_bit_cast(unsigned short, b);
    return (unsigned)ua | ((unsigned)ub << 16);
}
__device__ __forceinline__ unsigned pack2h(float x, float y) {
    auto h = __builtin_amdgcn_cvt_pkrtz(x, y);
    return __builtin_bit_cast(unsigned, h);
}

// ---------------- K1: BatchNorm stats (partial sums, no atomics) -------------
__global__ __launch_bounds__(256) void bn_stats(const float* __restrict__ H,
                                                float* __restrict__ part) {
    const int tid = threadIdx.x;
    const int cg = tid & 31;
    const int rg = tid >> 5;
    const float4* H4 = (const float4*)H;
    float4 s = {0,0,0,0}, q = {0,0,0,0};
    for (int r = blockIdx.x*8 + rg; r < NNODES; r += gridDim.x*8) {
        float4 v = H4[r*32 + cg];
        s.x += v.x; s.y += v.y; s.z += v.z; s.w += v.w;
        q.x = fmaf(v.x, v.x, q.x); q.y = fmaf(v.y, v.y, q.y);
        q.z = fmaf(v.z, v.z, q.z); q.w = fmaf(v.w, v.w, q.w);
    }
    __shared__ float red[8][32][8];
    red[rg][cg][0] = s.x; red[rg][cg][1] = s.y; red[rg][cg][2] = s.z; red[rg][cg][3] = s.w;
    red[rg][cg][4] = q.x; red[rg][cg][5] = q.y; red[rg][cg][6] = q.z; red[rg][cg][7] = q.w;
    __syncthreads();
    float v = 0.f;
    const int cg2 = tid >> 3, slot = tid & 7;
    #pragma unroll
    for (int g = 0; g < 8; ++g) v += red[g][cg2][slot];
    part[blockIdx.x*256 + tid] = v;
}

// ---------------- K2: finalize -> scale/shift --------------------------------
__global__ __launch_bounds__(256) void bn_finalize(const float* __restrict__ part,
                                                   const float* __restrict__ gamma,
                                                   const float* __restrict__ beta,
                                                   float* __restrict__ ss) {
    __shared__ float tot[256];
    const int t = threadIdx.x;
    float v = 0.f;
    for (int b = 0; b < NBLK_BN; ++b) v += part[b*256 + t];
    tot[t] = v;
    __syncthreads();
    if (t < 128) {
        const int cg = t >> 2, sl = t & 3;
        const float sum = tot[cg*8 + sl];
        const float sq  = tot[cg*8 + 4 + sl];
        const float mean = sum * (1.0f/NNODES);
        const float var  = sq * (1.0f/NNODES) - mean*mean;
        const float sc = rsqrtf(var + BN_EPS) * gamma[t];
        ss[t]       = sc;
        ss[128 + t] = beta[t] - mean*sc;
    }
}

// ---------------- K3: MFMA bf16 dual GEMM -> interleaved fp16 C rows ---------
// block: 512 thr (8 waves), tile 128M x 256N (N = [Wt 0..127 | Wo 128..255]),
// K-steps of 32. wave tile 64x64 (4x4 frags of 16x16x32).
__global__ __launch_bounds__(512) void dual_gemm_mfma(const float* __restrict__ H,
                                                      const float* __restrict__ ss,
                                                      const float* __restrict__ Wt,
                                                      const float* __restrict__ bt,
                                                      const float* __restrict__ Wo,
                                                      const float* __restrict__ bo,
                                                      unsigned* __restrict__ C32) {
    __shared__ short As[128][40];   // [row][k0..31], 80B stride (16B pad)
    __shared__ short Bs[256][40];   // [col][k0..31]
    const int tid  = threadIdx.x;
    const int lane = tid & 63;
    const int w    = tid >> 6;
    const int wr   = w >> 2, wc = w & 3;
    const int row0 = blockIdx.x * 128;
    const float4* H4  = (const float4*)H;
    const float4* ss4 = (const float4*)ss;

    f32x4 acc[4][4];
    #pragma unroll
    for (int a = 0; a < 4; ++a)
        #pragma unroll
        for (int b = 0; b < 4; ++b) acc[a][b] = (f32x4){0,0,0,0};

    const int lrow = lane & 15, lk = lane >> 4;

    for (int s = 0; s < 4; ++s) {          // K step: k in [32s, 32s+32)
        __syncthreads();
        { // stage A (BN applied, fp32 -> bf16)
            const int r = tid >> 2, cq = tid & 3;   // cq: 8-col group within slab
            const int row = row0 + r;
            float4 h0 = {0,0,0,0}, h1 = {0,0,0,0};
            if (row < NNODES) {
                h0 = H4[(size_t)row*32 + s*8 + cq*2];
                h1 = H4[(size_t)row*32 + s*8 + cq*2 + 1];
            }
            const float4 sc0 = ss4[s*8 + cq*2],      sc1 = ss4[s*8 + cq*2 + 1];
            const float4 sh0 = ss4[32 + s*8 + cq*2], sh1 = ss4[32 + s*8 + cq*2 + 1];
            uint4 aw;
            aw.x = pack2bf(fmaf(h0.x, sc0.x, sh0.x), fmaf(h0.y, sc0.y, sh0.y));
            aw.y = pack2bf(fmaf(h0.z, sc0.z, sh0.z), fmaf(h0.w, sc0.w, sh0.w));
            aw.z = pack2bf(fmaf(h1.x, sc1.x, sh1.x), fmaf(h1.y, sc1.y, sh1.y));
            aw.w = pack2bf(fmaf(h1.z, sc1.z, sh1.z), fmaf(h1.w, sc1.w, sh1.w));
            *(uint4*)&As[r][cq*8] = aw;
        }
        { // stage B (Wt | Wo, fp32 -> bf16, transposed to [col][k])
            const int colb = tid & 127;
            const int grp  = tid >> 7;             // 0..3
            const float* W = (grp & 2) ? Wo : Wt;
            const int kh   = grp & 1;              // k half (16 k's)
            float v[16];
            #pragma unroll
            for (int i = 0; i < 16; ++i)
                v[i] = W[(size_t)(s*32 + kh*16 + i)*128 + colb];
            uint4 b0, b1;
            b0.x = pack2bf(v[0],v[1]);  b0.y = pack2bf(v[2],v[3]);
            b0.z = pack2bf(v[4],v[5]);  b0.w = pack2bf(v[6],v[7]);
            b1.x = pack2bf(v[8],v[9]);  b1.y = pack2bf(v[10],v[11]);
            b1.z = pack2bf(v[12],v[13]); b1.w = pack2bf(v[14],v[15]);
            short* brow = &Bs[((grp & 2) ? 128 : 0) + colb][kh*16];
            *(uint4*)&brow[0] = b0;
            *(uint4*)&brow[8] = b1;
        }
        __syncthreads();
        short8 af[4], bf[4];
        #pragma unroll
        for (int mt = 0; mt < 4; ++mt)
            af[mt] = *(const short8*)&As[wr*64 + mt*16 + lrow][lk*8];
        #pragma unroll
        for (int nt = 0; nt < 4; ++nt)
            bf[nt] = *(const short8*)&Bs[wc*64 + nt*16 + lrow][lk*8];
        #pragma unroll
        for (int mt = 0; mt < 4; ++mt)
            #pragma unroll
            for (int nt = 0; nt < 4; ++nt)
                acc[mt][nt] = __builtin_amdgcn_mfma_f32_16x16x32_bf16(
                    af[mt], bf[nt], acc[mt][nt], 0, 0, 0);
    }

    // epilogue: +bias, pack fp16 col-pairs via shfl_xor(1), store dwords
    const bool isY = (wc >= 2);
    const float* bias = isY ? bo : bt;
    float bv[4];
    #pragma unroll
    for (int nt = 0; nt < 4; ++nt)
        bv[nt] = bias[(wc & 1)*64 + nt*16 + lrow];
    const int isodd = lane & 1;
    const int cp8   = (lane & 15) >> 1;
    const int ysel  = isY ? 1 : 0;
    #pragma unroll
    for (int mt = 0; mt < 4; ++mt) {
        #pragma unroll
        for (int ntp = 0; ntp < 2; ++ntp) {
            const int ntA = 2*ntp, ntB = ntA + 1;
            #pragma unroll
            for (int reg = 0; reg < 4; ++reg) {
                const float a = acc[mt][ntA][reg] + bv[ntA];
                const float b = acc[mt][ntB][reg] + bv[ntB];
                const float send = isodd ? a : b;
                const float got  = __shfl_xor(send, 1);
                const float lo = isodd ? got : a;
                const float hi = isodd ? b   : got;
                const unsigned pk = pack2h(lo, hi);
                const int nte = ntA + isodd;
                const int row = row0 + wr*64 + mt*16 + (lane >> 4)*4 + reg;
                const int dw  = 2*(32*(wc & 1) + 8*nte + cp8) + ysel;
                if (row < NNODES) C32[(size_t)row*128 + dw] = pk;
            }
        }
    }
}

// ---------------- K4: fused scores + softmax + aggregation -------------------
// one 64-lane wave per node; lane l owns col-pair (2l, 2l+1)
__device__ __forceinline__ float merge2(float A, float B, int lane, int m) {
    const bool hi = (lane & m) != 0;
    float t = hi ? A : B;
    t = __shfl_xor(t, m);
    return (hi ? B : A) + t;
}

__global__ __launch_bounds__(256) void fused_attn(const unsigned* __restrict__ C32,
                                                  const int* __restrict__ col,
                                                  float* __restrict__ outF,
                                                  float* __restrict__ Aout) {
    const int tid  = threadIdx.x;
    const int lane = tid & 63;
    const int i    = (blockIdx.x*256 + tid) >> 6;
    if (i >= NNODES) return;
    const uint2* Crow = (const uint2*)C32;

    const uint2 cv = Crow[(size_t)i*64 + lane];
    const h2_t a = __builtin_bit_cast(h2_t, cv.x);

    int myj = 0;
    if (lane < KNBR) myj = col[i*KNBR + lane];

    float p[KNBR];
    unsigned ybits[KNBR];
    #pragma unroll
    for (int k = 0; k < KNBR; ++k) {
        const int j = __builtin_amdgcn_readlane(myj, k);
        const uint2 v = Crow[(size_t)j*64 + lane];
        ybits[k] = v.y;
#if __has_builtin(__builtin_amdgcn_fdot2)
        p[k] = __builtin_amdgcn_fdot2(a, __builtin_bit_cast(h2_t, v.x), 0.0f, false);
#else
        { const h2_t b = __builtin_bit_cast(h2_t, v.x);
          p[k] = fmaf((float)a.x, (float)b.x, (float)a.y * (float)b.y); }
#endif
    }

    // merge-tree reduction: 17 values over 64 lanes
    // final: lane l holds dot[k] with k = (l&16) ? 16 : (l&15)
    float q0 = merge2(p[0],  p[1],  lane, 1);
    float q1 = merge2(p[2],  p[3],  lane, 1);
    float q2 = merge2(p[4],  p[5],  lane, 1);
    float q3 = merge2(p[6],  p[7],  lane, 1);
    float q4 = merge2(p[8],  p[9],  lane, 1);
    float q5 = merge2(p[10], p[11], lane, 1);
    float q6 = merge2(p[12], p[13], lane, 1);
    float q7 = merge2(p[14], p[15], lane, 1);
    float q8 = p[16] + __shfl_xor(p[16], 1);

    float r0 = merge2(q0, q1, lane, 2);
    float r1 = merge2(q2, q3, lane, 2);
    float r2 = merge2(q4, q5, lane, 2);
    float r3 = merge2(q6, q7, lane, 2);
    float r4 = q8 + __shfl_xor(q8, 2);

    float s0 = merge2(r0, r1, lane, 4);
    float s1 = merge2(r2, r3, lane, 4);
    float s2 = r4 + __shfl_xor(r4, 4);

    float t0 = merge2(s0, s1, lane, 8);
    float t1 = s2 + __shfl_xor(s2, 8);

    float u = merge2(t0, t1, lane, 16);
    u += __shfl_xor(u, 32);

    // sigmoid then exp (softmax without max-sub: sigmoid in (0,1), safe)
    const float sig = 1.0f / (1.0f + __expf(-u));
    const float e   = __expf(sig);
    const float me  = ((lane & 31) < KNBR) ? e : 0.0f;
    float S = me;
    S += __shfl_xor(S, 1);  S += __shfl_xor(S, 2);  S += __shfl_xor(S, 4);
    S += __shfl_xor(S, 8);  S += __shfl_xor(S, 16);
    const float rs = 1.0f / S;
    const float Alane = e * rs;

    if (lane < KNBR) Aout[(size_t)i*KNBR + lane] = Alane;

    // aggregation: acc += A_k * y_k  (A_k broadcast via readlane)
    const int Abits = __builtin_bit_cast(int, Alane);
    float acc0 = 0.f, acc1 = 0.f;
    #pragma unroll
    for (int k = 0; k < KNBR; ++k) {
        const int srcl = (k == 16) ? 16 : k;
        const float ak = __builtin_bit_cast(float, __builtin_amdgcn_readlane(Abits, srcl));
        const h2_t hy = __builtin_bit_cast(h2_t, ybits[k]);
        acc0 = fmaf(ak, (float)hy.x, acc0);
        acc1 = fmaf(ak, (float)hy.y, acc1);
    }
    acc0 = (acc0 >= 0.f) ? acc0 : SLOPE*acc0;
    acc1 = (acc1 >= 0.f) ? acc1 : SLOPE*acc1;
    float2 o = {acc0, acc1};
    *(float2*)&outF[(size_t)i*DF + 2*lane] = o;
}

extern "C" void kernel_launch(void* const* d_in, const int* in_sizes, int n_in,
                              void* d_out, int out_size, void* d_ws, size_t ws_size,
                              hipStream_t stream) {
    const float* H     = (const float*)d_in[0];
    const int*   col   = (const int*)  d_in[1];
    // d_in[2] = row (== e/17 analytically, unused)
    const float* gamma = (const float*)d_in[3];
    const float* beta  = (const float*)d_in[4];
    const float* Wt    = (const float*)d_in[5];
    const float* bt    = (const float*)d_in[6];
    const float* Wo    = (const float*)d_in[7];
    const float* bo    = (const float*)d_in[8];

    float* ws   = (float*)d_ws;
    float* part = ws + OFF_PART;
    float* ss   = ws + OFF_SS;
    unsigned* C32 = (unsigned*)(ws + OFF_C);

    float* outF = (float*)d_out;
    float* Aout = outF + (size_t)NNODES*DF;

    bn_stats      <<<dim3(NBLK_BN), dim3(256), 0, stream>>>(H, part);
    bn_finalize   <<<dim3(1),       dim3(256), 0, stream>>>(part, gamma, beta, ss);
    dual_gemm_mfma<<<dim3((NNODES+127)/128), dim3(512), 0, stream>>>(H, ss, Wt, bt, Wo, bo, C32);
    fused_attn    <<<dim3((NNODES+3)/4), dim3(256), 0, stream>>>(C32, col, outF, Aout);
}

// Round 6
// 94.559 us; speedup vs baseline: 1.9833x; 1.0606x over previous
//
#include <hip/hip_runtime.h>
#include <hip/hip_bf16.h>

#define NNODES 50000
#define KNBR   17
#define DF     128
#define NEDGE  (NNODES*KNBR)
#define BN_EPS 1e-5f
#define SLOPE  0.01f
#define NPAD   50048

// ---- workspace layout (in 4B words) ----
#define NBLK_BN 256
#define OFF_PART 0                            // 256 blocks * 256 floats
#define OFF_SS   (NBLK_BN*256)                // scale[128], shift[128]
#define OFF_T    (OFF_SS + 256)               // T32: NPAD rows x 64 uints (128 fp16 of Ht)
#define OFF_Y    (OFF_T + NPAD*64)            // Y32: NPAD rows x 64 uints (128 fp16 of Out)

typedef __fp16  h2_t   __attribute__((ext_vector_type(2)));
typedef short   short8 __attribute__((ext_vector_type(8)));
typedef float   f32x4  __attribute__((ext_vector_type(4)));
typedef float   f32x2  __attribute__((ext_vector_type(2)));

__device__ __forceinline__ unsigned pack2bf(float x, float y) {
    __hip_bfloat16 a = __float2bfloat16(x), b = __float2bfloat16(y);
    unsigned short ua = __builtin_bit_cast(unsigned short, a);
    unsigned short ub = __builtin_bit_cast(unsigned short, b);
    return (unsigned)ua | ((unsigned)ub << 16);
}
__device__ __forceinline__ unsigned pack2h(float x, float y) {
    auto h = __builtin_amdgcn_cvt_pkrtz(x, y);
    return __builtin_bit_cast(unsigned, h);
}

// ---------------- K1: BatchNorm stats (partial sums, no atomics) -------------
__global__ __launch_bounds__(256) void bn_stats(const float* __restrict__ H,
                                                float* __restrict__ part) {
    const int tid = threadIdx.x;
    const int cg = tid & 31;
    const int rg = tid >> 5;
    const float4* H4 = (const float4*)H;
    float4 s = {0,0,0,0}, q = {0,0,0,0};
    for (int r = blockIdx.x*8 + rg; r < NNODES; r += gridDim.x*8) {
        float4 v = H4[r*32 + cg];
        s.x += v.x; s.y += v.y; s.z += v.z; s.w += v.w;
        q.x = fmaf(v.x, v.x, q.x); q.y = fmaf(v.y, v.y, q.y);
        q.z = fmaf(v.z, v.z, q.z); q.w = fmaf(v.w, v.w, q.w);
    }
    __shared__ float red[8][32][8];
    red[rg][cg][0] = s.x; red[rg][cg][1] = s.y; red[rg][cg][2] = s.z; red[rg][cg][3] = s.w;
    red[rg][cg][4] = q.x; red[rg][cg][5] = q.y; red[rg][cg][6] = q.z; red[rg][cg][7] = q.w;
    __syncthreads();
    float v = 0.f;
    const int cg2 = tid >> 3, slot = tid & 7;
    #pragma unroll
    for (int g = 0; g < 8; ++g) v += red[g][cg2][slot];
    part[blockIdx.x*256 + tid] = v;
}

// ---------------- K2: finalize -> scale/shift --------------------------------
__global__ __launch_bounds__(256) void bn_finalize(const float* __restrict__ part,
                                                   const float* __restrict__ gamma,
                                                   const float* __restrict__ beta,
                                                   float* __restrict__ ss) {
    __shared__ float tot[256];
    const int t = threadIdx.x;
    float v = 0.f;
    for (int b = 0; b < NBLK_BN; ++b) v += part[b*256 + t];
    tot[t] = v;
    __syncthreads();
    if (t < 128) {
        const int cg = t >> 2, sl = t & 3;
        const float sum = tot[cg*8 + sl];
        const float sq  = tot[cg*8 + 4 + sl];
        const float mean = sum * (1.0f/NNODES);
        const float var  = sq * (1.0f/NNODES) - mean*mean;
        const float sc = rsqrtf(var + BN_EPS) * gamma[t];
        ss[t]       = sc;
        ss[128 + t] = beta[t] - mean*sc;
    }
}

// ---------------- K3: MFMA bf16 dual GEMM -> fp16 tables T (Ht) and Y (Out) --
// block 256 thr (4 waves), tile 64M x 256N; wave = 64x64; K-steps of 32.
// LDS layout: [row][48 shorts]; 16B k-group g stored at g ^ ((row>>2)&3).
__global__ __launch_bounds__(256) void dual_gemm_mfma(const float* __restrict__ H,
                                                      const float* __restrict__ ss,
                                                      const float* __restrict__ Wt,
                                                      const float* __restrict__ bt,
                                                      const float* __restrict__ Wo,
                                                      const float* __restrict__ bo,
                                                      unsigned* __restrict__ T32,
                                                      unsigned* __restrict__ Y32) {
    __shared__ short As[64][48];
    __shared__ short Bs[256][48];
    const int tid  = threadIdx.x;
    const int lane = tid & 63;
    const int wc   = tid >> 6;            // 0..3: which 64-col slab
    const int row0 = blockIdx.x * 64;
    const float4* H4  = (const float4*)H;
    const float4* ss4 = (const float4*)ss;

    f32x4 acc[4][4];
    #pragma unroll
    for (int a = 0; a < 4; ++a)
        #pragma unroll
        for (int b = 0; b < 4; ++b) acc[a][b] = (f32x4){0,0,0,0};

    const int lrow = lane & 15, lk = lane >> 4;

    for (int s = 0; s < 4; ++s) {          // K step: k in [32s, 32s+32)
        __syncthreads();
        { // stage A (BN applied, fp32 -> bf16): r=tid>>2, k-group cq=tid&3
            const int r = tid >> 2, cq = tid & 3;
            const int row = row0 + r;
            float4 h0 = {0,0,0,0}, h1 = {0,0,0,0};
            if (row < NNODES) {
                h0 = H4[(size_t)row*32 + s*8 + cq*2];
                h1 = H4[(size_t)row*32 + s*8 + cq*2 + 1];
            }
            const float4 sc0 = ss4[s*8 + cq*2],      sc1 = ss4[s*8 + cq*2 + 1];
            const float4 sh0 = ss4[32 + s*8 + cq*2], sh1 = ss4[32 + s*8 + cq*2 + 1];
            uint4 aw;
            aw.x = pack2bf(fmaf(h0.x, sc0.x, sh0.x), fmaf(h0.y, sc0.y, sh0.y));
            aw.y = pack2bf(fmaf(h0.z, sc0.z, sh0.z), fmaf(h0.w, sc0.w, sh0.w));
            aw.z = pack2bf(fmaf(h1.x, sc1.x, sh1.x), fmaf(h1.y, sc1.y, sh1.y));
            aw.w = pack2bf(fmaf(h1.z, sc1.z, sh1.z), fmaf(h1.w, sc1.w, sh1.w));
            const int g = cq ^ ((r >> 2) & 3);
            *(uint4*)&As[r][g*8] = aw;
        }
        { // stage B: thread c owns col c, all 32 k of this step
            const int c    = tid;
            const int colb = c & 127;
            const float* W = (c & 128) ? Wo : Wt;
            float v[32];
            #pragma unroll
            for (int i = 0; i < 32; ++i)
                v[i] = W[(size_t)(s*32 + i)*128 + colb];
            #pragma unroll
            for (int g = 0; g < 4; ++g) {
                uint4 bw;
                bw.x = pack2bf(v[8*g+0], v[8*g+1]);
                bw.y = pack2bf(v[8*g+2], v[8*g+3]);
                bw.z = pack2bf(v[8*g+4], v[8*g+5]);
                bw.w = pack2bf(v[8*g+6], v[8*g+7]);
                const int gs = g ^ ((c >> 2) & 3);
                *(uint4*)&Bs[c][gs*8] = bw;
            }
        }
        __syncthreads();
        short8 af[4], bf[4];
        #pragma unroll
        for (int mt = 0; mt < 4; ++mt) {
            const int r = mt*16 + lrow;
            const int g = lk ^ ((r >> 2) & 3);
            af[mt] = *(const short8*)&As[r][g*8];
        }
        #pragma unroll
        for (int nt = 0; nt < 4; ++nt) {
            const int cr = wc*64 + nt*16 + lrow;
            const int g  = lk ^ ((cr >> 2) & 3);
            bf[nt] = *(const short8*)&Bs[cr][g*8];
        }
        #pragma unroll
        for (int mt = 0; mt < 4; ++mt)
            #pragma unroll
            for (int nt = 0; nt < 4; ++nt)
                acc[mt][nt] = __builtin_amdgcn_mfma_f32_16x16x32_bf16(
                    af[mt], bf[nt], acc[mt][nt], 0, 0, 0);
    }

    // epilogue: +bias, pack fp16 col-pairs via shfl_xor(1), store dwords
    const bool isY = (wc >= 2);
    unsigned* dstT = isY ? Y32 : T32;
    const float* bias = isY ? bo : bt;
    float bv[4];
    #pragma unroll
    for (int nt = 0; nt < 4; ++nt)
        bv[nt] = bias[(wc & 1)*64 + nt*16 + lrow];
    const int isodd = lane & 1;
    const int cp8   = (lane & 15) >> 1;
    #pragma unroll
    for (int mt = 0; mt < 4; ++mt) {
        #pragma unroll
        for (int ntp = 0; ntp < 2; ++ntp) {
            const int ntA = 2*ntp, ntB = ntA + 1;
            #pragma unroll
            for (int reg = 0; reg < 4; ++reg) {
                const float a = acc[mt][ntA][reg] + bv[ntA];
                const float b = acc[mt][ntB][reg] + bv[ntB];
                const float send = isodd ? a : b;
                const float got  = __shfl_xor(send, 1);
                const float lo = isodd ? got : a;
                const float hi = isodd ? b   : got;
                const unsigned pk = pack2h(lo, hi);
                const int nte = ntA + isodd;
                const int row = row0 + mt*16 + (lane >> 4)*4 + reg;
                const int dw  = 32*(wc & 1) + 8*nte + cp8;
                if (row < NNODES) dstT[(size_t)row*64 + dw] = pk;
            }
        }
    }
}

// ---------------- K4a: scores + softmax -> A ---------------------------------
// one 64-lane wave per node; lane l owns col-pair (2l, 2l+1) (one uint)
__device__ __forceinline__ float merge2(float A, float B, int lane, int m) {
    const bool hi = (lane & m) != 0;
    float t = hi ? A : B;
    t = __shfl_xor(t, m);
    return (hi ? B : A) + t;
}

__global__ __launch_bounds__(256) void attn_scores(const unsigned* __restrict__ T32,
                                                   const int* __restrict__ col,
                                                   float* __restrict__ Aout) {
    const int tid  = threadIdx.x;
    const int lane = tid & 63;
    const int i    = (blockIdx.x*256 + tid) >> 6;
    if (i >= NNODES) return;

    const h2_t a = __builtin_bit_cast(h2_t, T32[(size_t)i*64 + lane]);

    int myj = 0;
    if (lane < KNBR) myj = col[i*KNBR + lane];

    float p[KNBR];
    #pragma unroll
    for (int k = 0; k < KNBR; ++k) {
        const int j = __builtin_amdgcn_readlane(myj, k);
        const unsigned v = T32[(size_t)j*64 + lane];
        p[k] = __builtin_amdgcn_fdot2(a, __builtin_bit_cast(h2_t, v), 0.0f, false);
    }

    // merge-tree reduction of 17 wave-wide dots
    float q0 = merge2(p[0],  p[1],  lane, 1);
    float q1 = merge2(p[2],  p[3],  lane, 1);
    float q2 = merge2(p[4],  p[5],  lane, 1);
    float q3 = merge2(p[6],  p[7],  lane, 1);
    float q4 = merge2(p[8],  p[9],  lane, 1);
    float q5 = merge2(p[10], p[11], lane, 1);
    float q6 = merge2(p[12], p[13], lane, 1);
    float q7 = merge2(p[14], p[15], lane, 1);
    float q8 = p[16] + __shfl_xor(p[16], 1);

    float r0 = merge2(q0, q1, lane, 2);
    float r1 = merge2(q2, q3, lane, 2);
    float r2 = merge2(q4, q5, lane, 2);
    float r3 = merge2(q6, q7, lane, 2);
    float r4 = q8 + __shfl_xor(q8, 2);

    float s0 = merge2(r0, r1, lane, 4);
    float s1 = merge2(r2, r3, lane, 4);
    float s2 = r4 + __shfl_xor(r4, 4);

    float t0 = merge2(s0, s1, lane, 8);
    float t1 = s2 + __shfl_xor(s2, 8);

    float u = merge2(t0, t1, lane, 16);
    u += __shfl_xor(u, 32);

    const float sig = 1.0f / (1.0f + __expf(-u));
    const float e   = __expf(sig);
    const float me  = ((lane & 31) < KNBR) ? e : 0.0f;
    float S = me;
    S += __shfl_xor(S, 1);  S += __shfl_xor(S, 2);  S += __shfl_xor(S, 4);
    S += __shfl_xor(S, 8);  S += __shfl_xor(S, 16);
    if (lane < KNBR) Aout[(size_t)i*KNBR + lane] = e / S;
}

// ---------------- K4b: A-weighted aggregation + LeakyReLU --------------------
__global__ __launch_bounds__(256) void attn_agg(const unsigned* __restrict__ Y32,
                                                const int* __restrict__ col,
                                                const float* __restrict__ Aout,
                                                float* __restrict__ outF) {
    const int tid  = threadIdx.x;
    const int lane = tid & 63;
    const int i    = (blockIdx.x*256 + tid) >> 6;
    if (i >= NNODES) return;

    int   myj = 0;
    float myA = 0.f;
    if (lane < KNBR) {
        myj = col[i*KNBR + lane];
        myA = Aout[(size_t)i*KNBR + lane];
    }
    const int Abits = __builtin_bit_cast(int, myA);

    float acc0 = 0.f, acc1 = 0.f;
    #pragma unroll
    for (int k = 0; k < KNBR; ++k) {
        const int j = __builtin_amdgcn_readlane(myj, k);
        const float ak = __builtin_bit_cast(float, __builtin_amdgcn_readlane(Abits, k));
        const h2_t y = __builtin_bit_cast(h2_t, Y32[(size_t)j*64 + lane]);
        acc0 = fmaf(ak, (float)y.x, acc0);
        acc1 = fmaf(ak, (float)y.y, acc1);
    }
    acc0 = (acc0 >= 0.f) ? acc0 : SLOPE*acc0;
    acc1 = (acc1 >= 0.f) ? acc1 : SLOPE*acc1;
    f32x2 o = {acc0, acc1};
    __builtin_nontemporal_store(o, (f32x2*)&outF[(size_t)i*DF + 2*lane]);
}

extern "C" void kernel_launch(void* const* d_in, const int* in_sizes, int n_in,
                              void* d_out, int out_size, void* d_ws, size_t ws_size,
                              hipStream_t stream) {
    const float* H     = (const float*)d_in[0];
    const int*   col   = (const int*)  d_in[1];
    // d_in[2] = row (== e/17 analytically, unused)
    const float* gamma = (const float*)d_in[3];
    const float* beta  = (const float*)d_in[4];
    const float* Wt    = (const float*)d_in[5];
    const float* bt    = (const float*)d_in[6];
    const float* Wo    = (const float*)d_in[7];
    const float* bo    = (const float*)d_in[8];

    float* ws   = (float*)d_ws;
    float* part = ws + OFF_PART;
    float* ss   = ws + OFF_SS;
    unsigned* T32 = (unsigned*)(ws + OFF_T);
    unsigned* Y32 = (unsigned*)(ws + OFF_Y);

    float* outF = (float*)d_out;
    float* Aout = outF + (size_t)NNODES*DF;

    bn_stats      <<<dim3(NBLK_BN), dim3(256), 0, stream>>>(H, part);
    bn_finalize   <<<dim3(1),       dim3(256), 0, stream>>>(part, gamma, beta, ss);
    dual_gemm_mfma<<<dim3((NNODES+63)/64), dim3(256), 0, stream>>>(H, ss, Wt, bt, Wo, bo, T32, Y32);
    attn_scores   <<<dim3((NNODES+3)/4), dim3(256), 0, stream>>>(T32, col, Aout);
    attn_agg      <<<dim3((NNODES+3)/4), dim3(256), 0, stream>>>(Y32, col, Aout, outF);
}